// Round 4
// baseline (102.602 us; speedup 1.0000x reference)
//
#include <hip/hip_runtime.h>
#include <hip/hip_bf16.h>

// NT-Xent (SimCLR) fused loss, MI355X gfx950. Round 4: fatten the tile.
// 256x256 tile per block (512 thr, 8 waves of 64x128), BK=64, 64KB LDS.
// Upper-triangle enumeration (32x17 wrapped); off-diag tiles feed row AND
// col sums. Sync semantics = round 3 (plain atomics, separate finalize).
//
// ws layout: [S: N floats][pos: N floats][zn: N*D bf16]

#define N_TOT 8192
#define BATCH 4096
#define DIM   256
#define BK    64
#define TM    256                    // tile edge
#define NT_TILES (N_TOT / TM)        // 32

typedef short bf16x8 __attribute__((ext_vector_type(8)));
typedef float f32x4  __attribute__((ext_vector_type(4)));

__device__ __forceinline__ void load_lds16(const void* g, void* l) {
  __builtin_amdgcn_global_load_lds(
      (const __attribute__((address_space(1))) unsigned int*)g,
      (__attribute__((address_space(3))) unsigned int*)l,
      16, 0, 0);
}

__device__ __forceinline__ unsigned short f32_to_bf16(float f) {
  unsigned int u = __float_as_uint(f);
  u += 0x7fff + ((u >> 16) & 1);   // RNE
  return (unsigned short)(u >> 16);
}

// One wave per row: 64 lanes x float4 = 256 elements. Also zeros S.
__global__ __launch_bounds__(256) void normalize_kernel(
    const float* __restrict__ z, unsigned short* __restrict__ zn,
    float* __restrict__ S) {
  const int wave = threadIdx.x >> 6;
  const int lane = threadIdx.x & 63;
  const int row  = blockIdx.x * 4 + wave;
  float4 v = ((const float4*)(z + (size_t)row * DIM))[lane];
  float ss = v.x * v.x + v.y * v.y + v.z * v.z + v.w * v.w;
#pragma unroll
  for (int m = 1; m <= 32; m <<= 1) ss += __shfl_xor(ss, m);
  float inv = 1.0f / sqrtf(ss);
  ushort4 o;
  o.x = f32_to_bf16(v.x * inv);
  o.y = f32_to_bf16(v.y * inv);
  o.z = f32_to_bf16(v.z * inv);
  o.w = f32_to_bf16(v.w * inv);
  ((ushort4*)(zn + (size_t)row * DIM))[lane] = o;
  if (threadIdx.x < 4) S[blockIdx.x * 4 + threadIdx.x] = 0.0f;
}

// Upper-triangle 256x256 tiles of sim = zn*zn^T*10, fused exp + row/col sums.
// Grid (17, 32): j = blockIdx.x in [0,16], rb_raw = blockIdx.y.
// cb_raw = (rb_raw + j) % 32; j==16 only for rb_raw < 16 (each unordered
// pair exactly once). 8 waves: wave = (wr<<1)|wc, wave quadrant 64x128.
__global__ __launch_bounds__(512, 2) void simclr_tile_kernel(
    const unsigned short* __restrict__ zn, float* __restrict__ S,
    float* __restrict__ pos) {
  const int j = blockIdx.x, rb_raw = blockIdx.y;
  if (j == 16 && rb_raw >= 16) return;

  const int tid = threadIdx.x;
  const int wave = tid >> 6, lane = tid & 63;
  const int wr = wave >> 1, wc = wave & 1;      // wave quadrant (4x2)
  const int c = lane & 15, quad = lane >> 4;    // MFMA lane coords

  int cb_raw = rb_raw + j;
  if (cb_raw >= NT_TILES) cb_raw -= NT_TILES;
  const int rb = (cb_raw < rb_raw) ? cb_raw : rb_raw;
  const int cb = (cb_raw < rb_raw) ? rb_raw : cb_raw;
  const bool isdiag = (j == 0);

  __shared__ alignas(16) unsigned short As[TM * BK];   // 32 KB
  __shared__ alignas(16) unsigned short Bs[TM * BK];   // 32 KB

  f32x4 acc[4][8];
#pragma unroll
  for (int i = 0; i < 4; ++i)
#pragma unroll
    for (int jj = 0; jj < 8; ++jj) acc[i][jj] = (f32x4){0.f, 0.f, 0.f, 0.f};

  // Staging: per issue a wave writes 8 rows x 64 bf16; lane l -> row +(l>>3),
  // LDS chunk (l&7); fetches global chunk (l&7)^(row&7) (XOR swizzle so
  // fragment ds_read_b128 are 2-way max = conflict-free; measured 0).
  const int srow   = lane >> 3;
  const int schunk = (lane & 7) ^ srow;
  const size_t a_row0 = (size_t)rb * TM;
  const size_t b_row0 = (size_t)cb * TM;

#pragma unroll
  for (int kb = 0; kb < DIM / BK; ++kb) {
#pragma unroll
    for (int t = 0; t < 4; ++t) {
      const int rloc = wave * 32 + t * 8 + srow;       // 0..255
      load_lds16(zn + (a_row0 + rloc) * DIM + kb * BK + schunk * 8,
                 As + rloc * BK + (lane & 7) * 8);
      load_lds16(zn + (b_row0 + rloc) * DIM + kb * BK + schunk * 8,
                 Bs + rloc * BK + (lane & 7) * 8);
    }
    __syncthreads();

#pragma unroll
    for (int kk = 0; kk < BK / 32; ++kk) {
      const int kc = kk * 4 + quad;
      const int sl = (kc ^ (c & 7)) * 8;               // de-swizzled offset
      bf16x8 af[4], bfr[8];
#pragma unroll
      for (int f = 0; f < 4; ++f)
        af[f] = *(const bf16x8*)(As + (wr * 64 + f * 16 + c) * BK + sl);
#pragma unroll
      for (int f = 0; f < 8; ++f)
        bfr[f] = *(const bf16x8*)(Bs + (wc * 128 + f * 16 + c) * BK + sl);
#pragma unroll
      for (int fm = 0; fm < 4; ++fm)
#pragma unroll
        for (int fn = 0; fn < 8; ++fn)
          acc[fm][fn] = __builtin_amdgcn_mfma_f32_16x16x32_bf16(
              af[fm], bfr[fn], acc[fm][fn], 0, 0, 0);
    }
    __syncthreads();
  }

  // Epilogue. C/D layout: row = quad*4 + reg, col = lane&15 per 16x16 frag.
  float cs[8] = {0.f, 0.f, 0.f, 0.f, 0.f, 0.f, 0.f, 0.f};
#pragma unroll
  for (int fm = 0; fm < 4; ++fm) {
#pragma unroll
    for (int r = 0; r < 4; ++r) {
      const int grow = rb * TM + wr * 64 + fm * 16 + quad * 4 + r;
      float s = 0.f;
#pragma unroll
      for (int fn = 0; fn < 8; ++fn) {
        const int gcol = cb * TM + wc * 128 + fn * 16 + c;
        const float logit = acc[fm][fn][r] * 10.0f;
        float e = __expf(logit);
        if (isdiag && gcol == grow) e = 0.f;     // exclude self-similarity
        if (!isdiag && gcol == grow + BATCH) {   // partner pair (i, i+B):
          pos[grow] = logit;                     // unique writer per element
          pos[gcol] = logit;                     // sim symmetric -> same value
        }
        s += e;
        cs[fn] += e;
      }
      s += __shfl_xor(s, 1);
      s += __shfl_xor(s, 2);
      s += __shfl_xor(s, 4);
      s += __shfl_xor(s, 8);
      if (c == 0) atomicAdd(&S[grow], s);
    }
  }
  if (!isdiag) {
    // column sums -> S[col] (transpose contribution of this tile)
#pragma unroll
    for (int fn = 0; fn < 8; ++fn) {
      cs[fn] += __shfl_xor(cs[fn], 16);
      cs[fn] += __shfl_xor(cs[fn], 32);
    }
    if (quad == 0) {
#pragma unroll
      for (int fn = 0; fn < 8; ++fn)
        atomicAdd(&S[cb * TM + wc * 128 + fn * 16 + c], cs[fn]);
    }
  }
}

// loss = mean(log(S_i) - pos_i)
__global__ __launch_bounds__(1024) void finalize_kernel(
    const float* __restrict__ S, const float* __restrict__ pos,
    float* __restrict__ out) {
  const int tid = threadIdx.x;
  float a = 0.f;
  for (int i = tid; i < N_TOT; i += 1024) a += __logf(S[i]) - pos[i];
#pragma unroll
  for (int m = 1; m <= 32; m <<= 1) a += __shfl_xor(a, m);
  __shared__ float red[16];
  if ((tid & 63) == 0) red[tid >> 6] = a;
  __syncthreads();
  if (tid < 16) {
    float v = red[tid];
    v += __shfl_xor(v, 1);
    v += __shfl_xor(v, 2);
    v += __shfl_xor(v, 4);
    v += __shfl_xor(v, 8);
    if (tid == 0) out[0] = v * (1.0f / (float)N_TOT);
  }
}

extern "C" void kernel_launch(void* const* d_in, const int* in_sizes, int n_in,
                              void* d_out, int out_size, void* d_ws,
                              size_t ws_size, hipStream_t stream) {
  const float* z = (const float*)d_in[0];
  float* out = (float*)d_out;
  char* ws = (char*)d_ws;
  float* S = (float*)ws;                                   // N floats
  float* pos = (float*)(ws + N_TOT * sizeof(float));       // N floats
  unsigned short* zn =
      (unsigned short*)(ws + 2 * N_TOT * sizeof(float));   // N*D bf16

  normalize_kernel<<<N_TOT / 4, 256, 0, stream>>>(z, zn, S);
  dim3 grid(17, NT_TILES);
  simclr_tile_kernel<<<grid, 512, 0, stream>>>(zn, S, pos);
  finalize_kernel<<<1, 1024, 0, stream>>>(S, pos, out);
}